// Round 8
// baseline (207.484 us; speedup 1.0000x reference)
//
#include <hip/hip_runtime.h>

#define T_  1024
#define B_  8
#define D_  768
#define H_  12
#define HD_ 64
#define BH_ 96
#define M_  8192           // T_*B_
#define XSZ 6291456ull     // T_*B_*D_
#define WSZ 589824ull      // D_*D_

typedef __attribute__((ext_vector_type(8))) short short8;
typedef __attribute__((ext_vector_type(4))) float f32x4;

__device__ __forceinline__ unsigned short f2bf(float f) {
    unsigned int u = __float_as_uint(f);
    u += 0x7FFF + ((u >> 16) & 1);          // round-to-nearest-even
    return (unsigned short)(u >> 16);
}

__device__ __forceinline__ void g2lds16(const unsigned short* g, unsigned short* l) {
    __builtin_amdgcn_global_load_lds(
        (const __attribute__((address_space(1))) unsigned int*)(g),
        (__attribute__((address_space(3))) unsigned int*)(l),
        16, 0, 0);
}

// ---------------------------------------------------------------------------
// Kernel 0: fp32 -> bf16 conversion of X (q,k,v) and the 7 weight matrices.
// ---------------------------------------------------------------------------
__global__ __launch_bounds__(256)
void convert_kernel(const float* __restrict__ q, const float* __restrict__ k,
                    const float* __restrict__ v,
                    const float* __restrict__ wq, const float* __restrict__ wk,
                    const float* __restrict__ wv, const float* __restrict__ wqm,
                    const float* __restrict__ wkm, const float* __restrict__ wvm,
                    const float* __restrict__ wo,
                    unsigned short* __restrict__ dst)
{
    const int seg = blockIdx.y;
    const float* s; size_t off, n;
    switch (seg) {
        case 0: s = q;   off = 0;               n = XSZ; break;
        case 1: s = k;   off = XSZ;             n = XSZ; break;
        case 2: s = v;   off = 2*XSZ;           n = XSZ; break;
        case 3: s = wq;  off = 3*XSZ;           n = WSZ; break;
        case 4: s = wk;  off = 3*XSZ +   WSZ;   n = WSZ; break;
        case 5: s = wv;  off = 3*XSZ + 2*WSZ;   n = WSZ; break;
        case 6: s = wqm; off = 3*XSZ + 3*WSZ;   n = WSZ; break;
        case 7: s = wkm; off = 3*XSZ + 4*WSZ;   n = WSZ; break;
        case 8: s = wvm; off = 3*XSZ + 5*WSZ;   n = WSZ; break;
        default:s = wo;  off = 3*XSZ + 6*WSZ;   n = WSZ; break;
    }
    unsigned short* d = dst + off;
    const size_t stride = (size_t)gridDim.x * blockDim.x;
    for (size_t i = (size_t)blockIdx.x * blockDim.x + threadIdx.x; i < n / 4; i += stride) {
        const float4 f = reinterpret_cast<const float4*>(s)[i];
        ushort4 o;
        o.x = f2bf(f.x); o.y = f2bf(f.y); o.z = f2bf(f.z); o.w = f2bf(f.w);
        reinterpret_cast<ushort4*>(d)[i] = o;
    }
}

// ---------------------------------------------------------------------------
// Shared GEMM core: C(128x128) = A(128xK) @ B(128xK)^T, bf16 MFMA 16x16x32,
// K=768, BK=64, 4 waves (2x2 quadrants).
// 3 LDS buffers (96 KB), DEPTH-2 prefetch, COUNTED vmcnt (T3+T4): steady
// state keeps 2 stages (16 insts) in flight; never drains vm queue in-loop.
// Coalesced staging (8 rows x 128B per wave-inst), XOR chunk swizzle via
// pre-swizzled global source + swizzled ds_read (rule 21).
// ---------------------------------------------------------------------------
__device__ __forceinline__ void stage_tile64(const unsigned short* __restrict__ A,
                                             const unsigned short* __restrict__ B,
                                             int m0, int n0, int ks,
                                             unsigned short* lds, int buf, int tid)
{
    const int w = tid >> 6, l = tid & 63;
    const int rsub = l >> 3;                  // row within 8-row group
    const int csw  = (l & 7) ^ rsub;          // pre-swizzled global chunk
    const int koff = ks * 64 + csw * 8;
    #pragma unroll
    for (int p = 0; p < 4; ++p) {
        const int rbase = p * 32 + w * 8;     // wave-uniform
        const int row   = rbase + rsub;
        g2lds16(&A[(size_t)(m0 + row) * D_ + koff],
                &lds[buf * 16384 + rbase * 64]);
        g2lds16(&B[(size_t)(n0 + row) * D_ + koff],
                &lds[buf * 16384 + 8192 + rbase * 64]);
    }
}

__device__ __forceinline__ void mfma_step64(const unsigned short* lds, int buf,
                                            int wr, int wc, int lr, int lg,
                                            f32x4 acc[4][4])
{
    #pragma unroll
    for (int kk = 0; kk < 2; ++kk) {
        short8 a[4], b[4];
        #pragma unroll
        for (int m = 0; m < 4; ++m) {
            const int row  = wr * 64 + 16 * m + lr;
            const int slot = (kk * 4 + lg) ^ (lr & 7);   // row&7 == lr&7
            a[m] = *reinterpret_cast<const short8*>(
                &lds[buf * 16384 + row * 64 + slot * 8]);
        }
        #pragma unroll
        for (int n = 0; n < 4; ++n) {
            const int row  = wc * 64 + 16 * n + lr;
            const int slot = (kk * 4 + lg) ^ (lr & 7);
            b[n] = *reinterpret_cast<const short8*>(
                &lds[buf * 16384 + 8192 + row * 64 + slot * 8]);
        }
        #pragma unroll
        for (int m = 0; m < 4; ++m)
            #pragma unroll
            for (int n = 0; n < 4; ++n)
                acc[m][n] = __builtin_amdgcn_mfma_f32_16x16x32_bf16(a[m], b[n], acc[m][n], 0, 0, 0);
    }
}

// 12 K-steps (K=768, BK=64), buffers ks%3, depth-2.
// Top wait: vmcnt(16) -> stage(ks) landed, stages ks+1,ks+2 stay in flight
// (8 insts each); tail ks=10/11 -> vmcnt(8)/(0).  After compute: lgkmcnt(0)
// + barrier retires ALL waves' ds_reads of buf ks%3, then stage(ks+3)
// safely overwrites it.  Stage flight = 2 full K-steps.
#define GEMM_CORE(Aptr, Bptr)                                                  \
    f32x4 acc[4][4];                                                           \
    _Pragma("unroll") for (int m = 0; m < 4; ++m)                              \
        _Pragma("unroll") for (int n = 0; n < 4; ++n)                          \
            acc[m][n] = (f32x4){0.f, 0.f, 0.f, 0.f};                           \
    stage_tile64(Aptr, Bptr, m0, n0, 0, lds, 0, tid);                          \
    stage_tile64(Aptr, Bptr, m0, n0, 1, lds, 1, tid);                          \
    stage_tile64(Aptr, Bptr, m0, n0, 2, lds, 2, tid);                          \
    for (int ks = 0; ks < 12; ++ks) {                                          \
        if (ks < 10)       { asm volatile("s_waitcnt vmcnt(16) lgkmcnt(0)" ::: "memory"); } \
        else if (ks == 10) { asm volatile("s_waitcnt vmcnt(8) lgkmcnt(0)" ::: "memory"); }  \
        else               { asm volatile("s_waitcnt vmcnt(0) lgkmcnt(0)" ::: "memory"); }  \
        __builtin_amdgcn_sched_barrier(0);                                     \
        __builtin_amdgcn_s_barrier();                                          \
        __builtin_amdgcn_sched_barrier(0);                                     \
        mfma_step64(lds, ks % 3, wr, wc, lr, lg, acc);                         \
        asm volatile("s_waitcnt lgkmcnt(0)" ::: "memory");                     \
        __builtin_amdgcn_sched_barrier(0);                                     \
        __builtin_amdgcn_s_barrier();                                          \
        __builtin_amdgcn_sched_barrier(0);                                     \
        if (ks < 9) stage_tile64(Aptr, Bptr, m0, n0, ks + 3, lds, (ks + 3) % 3, tid); \
    }

// ---------------------------------------------------------------------------
// Kernel 1: QKV projection GEMM (bf16 MFMA).  1-D grid, XCD-swizzled.
// q,k -> head layout [bh][t][64]; v -> transposed [bh][64][t].
// q scale folds hd^-0.5 AND log2(e): softmax runs in exp2 domain.
// ---------------------------------------------------------------------------
__global__ __launch_bounds__(256)
void qkv_gemm(const unsigned short* __restrict__ xb,
              const unsigned short* __restrict__ wb,
              const int* __restrict__ ls_ptr,
              const float* __restrict__ bq,  const float* __restrict__ bk,
              const float* __restrict__ bv,  const float* __restrict__ bqm,
              const float* __restrict__ bkm, const float* __restrict__ bvm,
              unsigned short* __restrict__ qh, unsigned short* __restrict__ kh,
              unsigned short* __restrict__ vt)
{
    __shared__ unsigned short lds[49152];   // 3 x 32 KB buffers (A+B)
    const int bid = blockIdx.x;                       // 1152 blocks
    const int L   = (bid & 7) * 144 + (bid >> 3);     // bijective XCD swizzle
    const int z   = L / 384;
    const int rem = L - z * 384;
    const int mi  = rem / 6;
    const int ni  = rem - mi * 6;
    const int m0 = mi * 128, n0 = ni * 128;

    const int tid = threadIdx.x;
    const int w = tid >> 6, l = tid & 63, lr = l & 15, lg = l >> 4;
    const int wr = w >> 1, wc = w & 1;

    const bool modal = (m0 >= ls_ptr[0] * B_);
    const unsigned short* A = xb + (size_t)z * XSZ;
    const unsigned short* W = wb + (size_t)(z + (modal ? 3 : 0)) * WSZ;
    const float* bias = modal ? (z == 0 ? bqm : z == 1 ? bkm : bvm)
                              : (z == 0 ? bq  : z == 1 ? bk  : bv);

    GEMM_CORE(A, W)

    float bn[4];
    #pragma unroll
    for (int n = 0; n < 4; ++n) bn[n] = bias[n0 + wc * 64 + 16 * n + lr];

    if (z < 2) {
        unsigned short* dst = (z == 0) ? qh : kh;
        // 0.125 * log2(e): scores emerge in log2 domain for flat softmax
        const float scale = (z == 0) ? 0.18033688011112042f : 1.0f;
        #pragma unroll
        for (int m = 0; m < 4; ++m) {
            const int grb = m0 + wr * 64 + 16 * m + 4 * lg;
            #pragma unroll
            for (int n = 0; n < 4; ++n) {
                const int gc = n0 + wc * 64 + 16 * n + lr;
                const int h = gc >> 6, e = gc & 63;
                #pragma unroll
                for (int j = 0; j < 4; ++j) {
                    const int gr = grb + j, t = gr >> 3, b = gr & 7;
                    dst[((size_t)(b * H_ + h) * T_ + t) * HD_ + e] =
                        f2bf((acc[m][n][j] + bn[n]) * scale);
                }
            }
        }
    } else {
        #pragma unroll
        for (int m = 0; m < 4; ++m) {
            const int grb = m0 + wr * 64 + 16 * m + 4 * lg;
            #pragma unroll
            for (int n = 0; n < 4; ++n) {
                const int gc = n0 + wc * 64 + 16 * n + lr;
                const int h = gc >> 6, e = gc & 63;
                #pragma unroll
                for (int j = 0; j < 4; ++j) {
                    const int gr = grb + j, t = gr >> 3, b = gr & 7;
                    vt[((size_t)(b * H_ + h) * HD_ + e) * T_ + t] =
                        f2bf(acc[m][n][j] + bn[n]);
                }
            }
        }
    }
}

// ---------------------------------------------------------------------------
// Kernel 3: output projection GEMM (bf16 MFMA), fp32 output + bias.
// ---------------------------------------------------------------------------
__global__ __launch_bounds__(256)
void out_gemm(const unsigned short* __restrict__ aob,
              const unsigned short* __restrict__ wo,
              const float* __restrict__ bo, float* __restrict__ out)
{
    __shared__ unsigned short lds[49152];
    const int bid = blockIdx.x;                      // 384 blocks
    const int L   = (bid & 7) * 48 + (bid >> 3);
    const int mi  = L / 6, ni = L - mi * 6;
    const int m0 = mi * 128, n0 = ni * 128;

    const int tid = threadIdx.x;
    const int w = tid >> 6, l = tid & 63, lr = l & 15, lg = l >> 4;
    const int wr = w >> 1, wc = w & 1;

    GEMM_CORE(aob, wo)

    float bn[4];
    #pragma unroll
    for (int n = 0; n < 4; ++n) bn[n] = bo[n0 + wc * 64 + 16 * n + lr];

    #pragma unroll
    for (int m = 0; m < 4; ++m) {
        const int grb = m0 + wr * 64 + 16 * m + 4 * lg;
        #pragma unroll
        for (int n = 0; n < 4; ++n) {
            const int gc = n0 + wc * 64 + 16 * n + lr;
            #pragma unroll
            for (int j = 0; j < 4; ++j) {
                const int gr = grb + j;
                out[(size_t)gr * D_ + gc] = acc[m][n][j] + bn[n];
            }
        }
    }
}

// ---------------------------------------------------------------------------
// Kernel 2: flash attention, bf16 MFMA, FLAT softmax (exp2 domain, no
// reductions); row-sum via ones-column MFMA.  Unchanged from R6.
// ---------------------------------------------------------------------------
__global__ __launch_bounds__(256)
void attn_kernel_bf16(const unsigned short* __restrict__ qh,
                      const unsigned short* __restrict__ kh,
                      const unsigned short* __restrict__ vt,
                      unsigned short* __restrict__ aob)
{
    const int bid = blockIdx.x;                      // 1536 blocks
    const int L   = (bid & 7) * 192 + (bid >> 3);
    const int bh  = L >> 4;
    const int qt  = L & 15;

    const int tid = threadIdx.x;
    const int w   = tid >> 6;
    const int l   = tid & 63;
    const int lr  = l & 15;
    const int lg  = l >> 4;

    __shared__ unsigned short Ks[64 * 64];
    __shared__ unsigned short Vt[64 * 64];
    __shared__ unsigned short Ps[64 * 64];

    const size_t qk_head = (size_t)bh * T_ * HD_;
    const size_t vt_head = (size_t)bh * HD_ * T_;

    short8 qf[2];
    #pragma unroll
    for (int c = 0; c < 2; ++c)
        qf[c] = *reinterpret_cast<const short8*>(
            &qh[qk_head + (size_t)(qt * 64 + 16 * w + lr) * HD_ + 8 * lg + 32 * c]);

    const short one_bf = (short)0x3F80;   // bf16 1.0
    const short8 ones8 = {one_bf, one_bf, one_bf, one_bf,
                          one_bf, one_bf, one_bf, one_bf};

    f32x4 o[4];
    #pragma unroll
    for (int ef = 0; ef < 4; ++ef) o[ef] = (f32x4){0.f, 0.f, 0.f, 0.f};
    f32x4 lsumf = (f32x4){0.f, 0.f, 0.f, 0.f};

    for (int kt = 0; kt < 16; ++kt) {
        __syncthreads();
        #pragma unroll
        for (int p = 0; p < 2; ++p) {
            const int slot = tid + p * 256;
            const int row  = slot >> 3;
            const int ch   = slot & 7;
            const int sw   = (ch ^ (row & 7)) * 8;
            const short8 kd = *reinterpret_cast<const short8*>(
                &kh[qk_head + (size_t)(kt * 64 + row) * HD_ + 8 * ch]);
            *reinterpret_cast<short8*>(&Ks[row * 64 + sw]) = kd;
            const short8 vd = *reinterpret_cast<const short8*>(
                &vt[vt_head + (size_t)row * T_ + kt * 64 + 8 * ch]);
            *reinterpret_cast<short8*>(&Vt[row * 64 + sw]) = vd;
        }
        __syncthreads();

        // ---- S = Q K^T (log2 domain): 8 MFMA ----
        f32x4 s[4];
        #pragma unroll
        for (int nf = 0; nf < 4; ++nf) s[nf] = (f32x4){0.f, 0.f, 0.f, 0.f};
        #pragma unroll
        for (int c = 0; c < 2; ++c) {
            #pragma unroll
            for (int nf = 0; nf < 4; ++nf) {
                const int row = 16 * nf + lr;
                const short8 kb = *reinterpret_cast<const short8*>(
                    &Ks[row * 64 + ((8 * lg + 32 * c) ^ ((row & 7) << 3))]);
                s[nf] = __builtin_amdgcn_mfma_f32_16x16x32_bf16(qf[c], kb, s[nf], 0, 0, 0);
            }
        }

        // ---- flat softmax: P = exp2(s - 16), no reductions ----
        #pragma unroll
        for (int r = 0; r < 4; ++r) {
            const int q  = 16 * w + 4 * lg + r;
            const int qx = ((4 * lg + r) & 7) << 3;
            #pragma unroll
            for (int nf = 0; nf < 4; ++nf)
                Ps[q * 64 + ((16 * nf + lr) ^ qx)] =
                    f2bf(exp2f(s[nf][r] - 16.0f));
        }
        __syncthreads();

        // ---- O += P V ; lsum += P 1 : 10 MFMA ----
        const int prow = 16 * w + lr;
        #pragma unroll
        for (int c = 0; c < 2; ++c) {
            const short8 pa = *reinterpret_cast<const short8*>(
                &Ps[prow * 64 + ((8 * lg + 32 * c) ^ ((prow & 7) << 3))]);
            #pragma unroll
            for (int ef = 0; ef < 4; ++ef) {
                const int vrow = 16 * ef + lr;
                const short8 vb = *reinterpret_cast<const short8*>(
                    &Vt[vrow * 64 + ((8 * lg + 32 * c) ^ ((vrow & 7) << 3))]);
                o[ef] = __builtin_amdgcn_mfma_f32_16x16x32_bf16(pa, vb, o[ef], 0, 0, 0);
            }
            lsumf = __builtin_amdgcn_mfma_f32_16x16x32_bf16(pa, ones8, lsumf, 0, 0, 0);
        }
    }

    const int b = bh / H_, h = bh % H_;
    #pragma unroll
    for (int r = 0; r < 4; ++r) {
        const int t = qt * 64 + 16 * w + 4 * lg + r;
        const float inv = 1.0f / lsumf[r];
        #pragma unroll
        for (int ef = 0; ef < 4; ++ef)
            aob[((size_t)t * B_ + b) * D_ + h * HD_ + 16 * ef + lr] =
                f2bf(o[ef][r] * inv);
    }
}

// ---------------------------------------------------------------------------
extern "C" void kernel_launch(void* const* d_in, const int* in_sizes, int n_in,
                              void* d_out, int out_size, void* d_ws, size_t ws_size,
                              hipStream_t stream)
{
    const float* query = (const float*)d_in[0];
    const float* keyi  = (const float*)d_in[1];
    const float* value = (const float*)d_in[2];
    const int*   lsp   = (const int*)  d_in[3];
    const float* Wq  = (const float*)d_in[4],  *bq  = (const float*)d_in[5];
    const float* Wk  = (const float*)d_in[6],  *bk  = (const float*)d_in[7];
    const float* Wv  = (const float*)d_in[8],  *bv  = (const float*)d_in[9];
    const float* Wqm = (const float*)d_in[10], *bqm = (const float*)d_in[11];
    const float* Wkm = (const float*)d_in[12], *bkm = (const float*)d_in[13];
    const float* Wvm = (const float*)d_in[14], *bvm = (const float*)d_in[15];
    const float* Wo  = (const float*)d_in[16], *bo  = (const float*)d_in[17];

    unsigned short* ws = (unsigned short*)d_ws;
    unsigned short* xb  = ws;                       // 3*XSZ
    unsigned short* wb  = xb + 3 * XSZ;             // 7*WSZ
    unsigned short* qh  = wb + 7 * WSZ;             // XSZ
    unsigned short* kh  = qh + XSZ;                 // XSZ
    unsigned short* vt  = kh + XSZ;                 // XSZ
    unsigned short* aob = vt + XSZ;                 // XSZ

    dim3 gc_(512, 10);
    convert_kernel<<<gc_, 256, 0, stream>>>(query, keyi, value,
                                            Wq, Wk, Wv, Wqm, Wkm, Wvm, Wo, xb);

    qkv_gemm<<<1152, 256, 0, stream>>>(xb, wb, lsp, bq, bk, bv, bqm, bkm, bvm,
                                       qh, kh, vt);

    attn_kernel_bf16<<<1536, 256, 0, stream>>>(qh, kh, vt, aob);

    out_gemm<<<384, 256, 0, stream>>>(aob, wb + 6 * WSZ, bo, (float*)d_out);
}

// Round 9
// 187.445 us; speedup vs baseline: 1.1069x; 1.1069x over previous
//
#include <hip/hip_runtime.h>

#define T_  1024
#define B_  8
#define D_  768
#define H_  12
#define HD_ 64
#define BH_ 96
#define M_  8192           // T_*B_
#define XSZ 6291456ull     // T_*B_*D_
#define WSZ 589824ull      // D_*D_

typedef __attribute__((ext_vector_type(8))) short short8;
typedef __attribute__((ext_vector_type(4))) float f32x4;

__device__ __forceinline__ unsigned short f2bf(float f) {
    unsigned int u = __float_as_uint(f);
    u += 0x7FFF + ((u >> 16) & 1);          // round-to-nearest-even
    return (unsigned short)(u >> 16);
}

__device__ __forceinline__ void g2lds16(const unsigned short* g, unsigned short* l) {
    __builtin_amdgcn_global_load_lds(
        (const __attribute__((address_space(1))) unsigned int*)(g),
        (__attribute__((address_space(3))) unsigned int*)(l),
        16, 0, 0);
}

// ---------------------------------------------------------------------------
// Kernel 0: fp32 -> bf16 conversion of X (q,k,v) and the 7 weight matrices.
// ---------------------------------------------------------------------------
__global__ __launch_bounds__(256)
void convert_kernel(const float* __restrict__ q, const float* __restrict__ k,
                    const float* __restrict__ v,
                    const float* __restrict__ wq, const float* __restrict__ wk,
                    const float* __restrict__ wv, const float* __restrict__ wqm,
                    const float* __restrict__ wkm, const float* __restrict__ wvm,
                    const float* __restrict__ wo,
                    unsigned short* __restrict__ dst)
{
    const int seg = blockIdx.y;
    const float* s; size_t off, n;
    switch (seg) {
        case 0: s = q;   off = 0;               n = XSZ; break;
        case 1: s = k;   off = XSZ;             n = XSZ; break;
        case 2: s = v;   off = 2*XSZ;           n = XSZ; break;
        case 3: s = wq;  off = 3*XSZ;           n = WSZ; break;
        case 4: s = wk;  off = 3*XSZ +   WSZ;   n = WSZ; break;
        case 5: s = wv;  off = 3*XSZ + 2*WSZ;   n = WSZ; break;
        case 6: s = wqm; off = 3*XSZ + 3*WSZ;   n = WSZ; break;
        case 7: s = wkm; off = 3*XSZ + 4*WSZ;   n = WSZ; break;
        case 8: s = wvm; off = 3*XSZ + 5*WSZ;   n = WSZ; break;
        default:s = wo;  off = 3*XSZ + 6*WSZ;   n = WSZ; break;
    }
    unsigned short* d = dst + off;
    const size_t stride = (size_t)gridDim.x * blockDim.x;
    for (size_t i = (size_t)blockIdx.x * blockDim.x + threadIdx.x; i < n / 4; i += stride) {
        const float4 f = reinterpret_cast<const float4*>(s)[i];
        ushort4 o;
        o.x = f2bf(f.x); o.y = f2bf(f.y); o.z = f2bf(f.z); o.w = f2bf(f.w);
        reinterpret_cast<ushort4*>(d)[i] = o;
    }
}

// ---------------------------------------------------------------------------
// Shared GEMM core: C(128x128) = A(128xK) @ B(128xK)^T, bf16 MFMA 16x16x32,
// K=768, BK=32, 4 waves (2x2 quadrants), 2 x 16 KB LDS buffers (32 KB ->
// 4 blocks/CU for TLP).  Coalesced staging (16 rows x 64B per wave-inst =
// 16 lines, optimal).  2-bit chunk XOR  c ^= (row>>1)&3  spreads the 64B-row
// fragment reads across all 8 bank-groups (8 words/bank = conflict-free
// floor); applied as pre-swizzled GLOBAL source + swizzled ds_read (rule 21).
// ---------------------------------------------------------------------------
__device__ __forceinline__ void stage_tile32(const unsigned short* __restrict__ A,
                                             const unsigned short* __restrict__ B,
                                             int m0, int n0, int ks,
                                             unsigned short* lds, int buf, int tid)
{
    const int w = tid >> 6, l = tid & 63;
    const int rsub = l >> 2;                        // row within 16-row group
    const int cg   = (l & 3) ^ ((l >> 3) & 3);      // pre-swizzled global chunk
    const int koff = ks * 32 + cg * 8;
    #pragma unroll
    for (int p = 0; p < 2; ++p) {
        const int rbase = p * 64 + w * 16;          // wave-uniform
        const int row   = rbase + rsub;
        g2lds16(&A[(size_t)(m0 + row) * D_ + koff],
                &lds[buf * 8192 + rbase * 32]);
        g2lds16(&B[(size_t)(n0 + row) * D_ + koff],
                &lds[buf * 8192 + 4096 + rbase * 32]);
    }
}

__device__ __forceinline__ void mfma_step32(const unsigned short* lds, int buf,
                                            int wr, int wc, int lr, int lg,
                                            f32x4 acc[4][4])
{
    const int slot = (lg ^ ((lr >> 1) & 3)) * 8;    // (row>>1)&3 == (lr>>1)&3
    short8 a[4], b[4];
    #pragma unroll
    for (int m = 0; m < 4; ++m)
        a[m] = *reinterpret_cast<const short8*>(
            &lds[buf * 8192 + (wr * 64 + 16 * m + lr) * 32 + slot]);
    #pragma unroll
    for (int n = 0; n < 4; ++n)
        b[n] = *reinterpret_cast<const short8*>(
            &lds[buf * 8192 + 4096 + (wc * 64 + 16 * n + lr) * 32 + slot]);
    #pragma unroll
    for (int m = 0; m < 4; ++m)
        #pragma unroll
        for (int n = 0; n < 4; ++n)
            acc[m][n] = __builtin_amdgcn_mfma_f32_16x16x32_bf16(a[m], b[n], acc[m][n], 0, 0, 0);
}

// 24 K-steps (K=768, BK=32).  2-phase: stage(ks+1) issued before compute of
// buf[ks&1]; vmcnt(0)+lgkmcnt(0) before the single end barrier.  Cross-block
// TLP (4 blocks/CU) hides the drain.
#define GEMM_CORE(Aptr, Bptr)                                                  \
    f32x4 acc[4][4];                                                           \
    _Pragma("unroll") for (int m = 0; m < 4; ++m)                              \
        _Pragma("unroll") for (int n = 0; n < 4; ++n)                          \
            acc[m][n] = (f32x4){0.f, 0.f, 0.f, 0.f};                           \
    stage_tile32(Aptr, Bptr, m0, n0, 0, lds, 0, tid);                          \
    asm volatile("s_waitcnt vmcnt(0)" ::: "memory");                           \
    __builtin_amdgcn_s_barrier();                                              \
    for (int ks = 0; ks < 24; ++ks) {                                          \
        __builtin_amdgcn_sched_barrier(0);                                     \
        if (ks < 23) stage_tile32(Aptr, Bptr, m0, n0, ks + 1, lds, (ks + 1) & 1, tid); \
        mfma_step32(lds, ks & 1, wr, wc, lr, lg, acc);                         \
        asm volatile("s_waitcnt vmcnt(0) lgkmcnt(0)" ::: "memory");            \
        __builtin_amdgcn_sched_barrier(0);                                     \
        __builtin_amdgcn_s_barrier();                                          \
        __builtin_amdgcn_sched_barrier(0);                                     \
    }

// ---------------------------------------------------------------------------
// Kernel 1: QKV projection GEMM (bf16 MFMA).  1-D grid, XCD-swizzled.
// q,k -> head layout [bh][t][64]; v -> transposed [bh][64][t].
// q scale folds hd^-0.5 AND log2(e): softmax runs in exp2 domain.
// ---------------------------------------------------------------------------
__global__ __launch_bounds__(256)
void qkv_gemm(const unsigned short* __restrict__ xb,
              const unsigned short* __restrict__ wb,
              const int* __restrict__ ls_ptr,
              const float* __restrict__ bq,  const float* __restrict__ bk,
              const float* __restrict__ bv,  const float* __restrict__ bqm,
              const float* __restrict__ bkm, const float* __restrict__ bvm,
              unsigned short* __restrict__ qh, unsigned short* __restrict__ kh,
              unsigned short* __restrict__ vt)
{
    __shared__ unsigned short lds[16384];   // 2 x 16 KB buffers (A+B)
    const int bid = blockIdx.x;                       // 1152 blocks
    const int L   = (bid & 7) * 144 + (bid >> 3);     // bijective XCD swizzle
    const int z   = L / 384;
    const int rem = L - z * 384;
    const int mi  = rem / 6;
    const int ni  = rem - mi * 6;
    const int m0 = mi * 128, n0 = ni * 128;

    const int tid = threadIdx.x;
    const int w = tid >> 6, l = tid & 63, lr = l & 15, lg = l >> 4;
    const int wr = w >> 1, wc = w & 1;

    const bool modal = (m0 >= ls_ptr[0] * B_);
    const unsigned short* A = xb + (size_t)z * XSZ;
    const unsigned short* W = wb + (size_t)(z + (modal ? 3 : 0)) * WSZ;
    const float* bias = modal ? (z == 0 ? bqm : z == 1 ? bkm : bvm)
                              : (z == 0 ? bq  : z == 1 ? bk  : bv);

    GEMM_CORE(A, W)

    float bn[4];
    #pragma unroll
    for (int n = 0; n < 4; ++n) bn[n] = bias[n0 + wc * 64 + 16 * n + lr];

    if (z < 2) {
        unsigned short* dst = (z == 0) ? qh : kh;
        // 0.125 * log2(e): scores emerge in log2 domain for flat softmax
        const float scale = (z == 0) ? 0.18033688011112042f : 1.0f;
        #pragma unroll
        for (int m = 0; m < 4; ++m) {
            const int grb = m0 + wr * 64 + 16 * m + 4 * lg;
            #pragma unroll
            for (int n = 0; n < 4; ++n) {
                const int gc = n0 + wc * 64 + 16 * n + lr;
                const int h = gc >> 6, e = gc & 63;
                #pragma unroll
                for (int j = 0; j < 4; ++j) {
                    const int gr = grb + j, t = gr >> 3, b = gr & 7;
                    dst[((size_t)(b * H_ + h) * T_ + t) * HD_ + e] =
                        f2bf((acc[m][n][j] + bn[n]) * scale);
                }
            }
        }
    } else {
        #pragma unroll
        for (int m = 0; m < 4; ++m) {
            const int grb = m0 + wr * 64 + 16 * m + 4 * lg;
            #pragma unroll
            for (int n = 0; n < 4; ++n) {
                const int gc = n0 + wc * 64 + 16 * n + lr;
                const int h = gc >> 6, e = gc & 63;
                #pragma unroll
                for (int j = 0; j < 4; ++j) {
                    const int gr = grb + j, t = gr >> 3, b = gr & 7;
                    vt[((size_t)(b * H_ + h) * HD_ + e) * T_ + t] =
                        f2bf(acc[m][n][j] + bn[n]);
                }
            }
        }
    }
}

// ---------------------------------------------------------------------------
// Kernel 3: output projection GEMM (bf16 MFMA), fp32 output + bias.
// ---------------------------------------------------------------------------
__global__ __launch_bounds__(256)
void out_gemm(const unsigned short* __restrict__ aob,
              const unsigned short* __restrict__ wo,
              const float* __restrict__ bo, float* __restrict__ out)
{
    __shared__ unsigned short lds[16384];
    const int bid = blockIdx.x;                      // 384 blocks
    const int L   = (bid & 7) * 48 + (bid >> 3);
    const int mi  = L / 6, ni = L - mi * 6;
    const int m0 = mi * 128, n0 = ni * 128;

    const int tid = threadIdx.x;
    const int w = tid >> 6, l = tid & 63, lr = l & 15, lg = l >> 4;
    const int wr = w >> 1, wc = w & 1;

    GEMM_CORE(aob, wo)

    float bn[4];
    #pragma unroll
    for (int n = 0; n < 4; ++n) bn[n] = bo[n0 + wc * 64 + 16 * n + lr];

    #pragma unroll
    for (int m = 0; m < 4; ++m) {
        const int grb = m0 + wr * 64 + 16 * m + 4 * lg;
        #pragma unroll
        for (int n = 0; n < 4; ++n) {
            const int gc = n0 + wc * 64 + 16 * n + lr;
            #pragma unroll
            for (int j = 0; j < 4; ++j) {
                const int gr = grb + j;
                out[(size_t)gr * D_ + gc] = acc[m][n][j] + bn[n];
            }
        }
    }
}

// ---------------------------------------------------------------------------
// Kernel 2: flash attention, bf16 MFMA, flat softmax (exp2 domain).
// 128 q-rows/block, 512 threads (8 waves x 16 rows).  K/V double-buffered
// via global_load_lds (pre-swizzled source); stage(kt+1) issued at top of
// iter, waited only at the end -> full compute phase of load flight.
// 768 blocks @ 3 blocks/CU = all co-resident.
// ---------------------------------------------------------------------------
__device__ __forceinline__ void stage_kv(const unsigned short* __restrict__ khh,
                                         const unsigned short* __restrict__ vth,
                                         int kt, unsigned short* KsB,
                                         unsigned short* VtB, int w, int l)
{
    const int rbase = w * 8;                    // wave-uniform (8 waves x 8 rows)
    const int row   = rbase + (l >> 3);
    const int cg    = (l & 7) ^ ((l >> 3) & 7); // pre-swizzled global chunk
    g2lds16(&khh[(size_t)(kt * 64 + row) * HD_ + cg * 8], &KsB[rbase * 64]);
    g2lds16(&vth[(size_t)row * T_ + kt * 64 + cg * 8],    &VtB[rbase * 64]);
}

__global__ __launch_bounds__(512)
void attn_kernel_bf16(const unsigned short* __restrict__ qh,
                      const unsigned short* __restrict__ kh,
                      const unsigned short* __restrict__ vt,
                      unsigned short* __restrict__ aob)
{
    const int bid = blockIdx.x;                      // 768 blocks
    const int L   = (bid & 7) * 96 + (bid >> 3);     // 12 heads per XCD
    const int bh  = L >> 3;
    const int qt  = L & 7;                           // 8 q-tiles of 128 rows

    const int tid = threadIdx.x;
    const int w   = tid >> 6;                        // 0..7
    const int l   = tid & 63;
    const int lr  = l & 15;
    const int lg  = l >> 4;

    __shared__ unsigned short Ks[2][4096];   // [buf][64 rows][64] swizzled
    __shared__ unsigned short Vt[2][4096];
    __shared__ unsigned short Ps[8192];      // [128 q][64 s]   swizzled

    const unsigned short* khh = kh + (size_t)bh * T_ * HD_;
    const unsigned short* vth = vt + (size_t)bh * HD_ * T_;
    const size_t qk_head = (size_t)bh * T_ * HD_;

    short8 qf[2];
    #pragma unroll
    for (int c = 0; c < 2; ++c)
        qf[c] = *reinterpret_cast<const short8*>(
            &qh[qk_head + (size_t)(qt * 128 + 16 * w + lr) * HD_ + 8 * lg + 32 * c]);

    const short one_bf = (short)0x3F80;   // bf16 1.0
    const short8 ones8 = {one_bf, one_bf, one_bf, one_bf,
                          one_bf, one_bf, one_bf, one_bf};

    f32x4 o[4];
    #pragma unroll
    for (int ef = 0; ef < 4; ++ef) o[ef] = (f32x4){0.f, 0.f, 0.f, 0.f};
    f32x4 lsumf = (f32x4){0.f, 0.f, 0.f, 0.f};

    stage_kv(khh, vth, 0, Ks[0], Vt[0], w, l);
    asm volatile("s_waitcnt vmcnt(0)" ::: "memory");
    __builtin_amdgcn_s_barrier();

    int buf = 0;
    for (int kt = 0; kt < 16; ++kt) {
        __builtin_amdgcn_sched_barrier(0);
        if (kt < 15)
            stage_kv(khh, vth, kt + 1, Ks[buf ^ 1], Vt[buf ^ 1], w, l);

        // ---- S = Q K^T (log2 domain): 8 MFMA ----
        f32x4 s[4];
        #pragma unroll
        for (int nf = 0; nf < 4; ++nf) s[nf] = (f32x4){0.f, 0.f, 0.f, 0.f};
        #pragma unroll
        for (int c = 0; c < 2; ++c) {
            #pragma unroll
            for (int nf = 0; nf < 4; ++nf) {
                const short8 kb = *reinterpret_cast<const short8*>(
                    &Ks[buf][(16 * nf + lr) * 64 + ((8 * lg + 32 * c) ^ ((lr & 7) << 3))]);
                s[nf] = __builtin_amdgcn_mfma_f32_16x16x32_bf16(qf[c], kb, s[nf], 0, 0, 0);
            }
        }

        // ---- flat softmax: P = exp2(s - 16), no reductions ----
        #pragma unroll
        for (int r = 0; r < 4; ++r) {
            const int q  = 16 * w + 4 * lg + r;
            const int qx = ((4 * lg + r) & 7) << 3;
            #pragma unroll
            for (int nf = 0; nf < 4; ++nf)
                Ps[q * 64 + ((16 * nf + lr) ^ qx)] =
                    f2bf(exp2f(s[nf][r] - 16.0f));
        }
        asm volatile("s_waitcnt lgkmcnt(0)" ::: "memory");
        __builtin_amdgcn_sched_barrier(0);
        __builtin_amdgcn_s_barrier();
        __builtin_amdgcn_sched_barrier(0);

        // ---- O += P V ; lsum += P 1 : 10 MFMA ----
        const int prow = 16 * w + lr;
        #pragma unroll
        for (int c = 0; c < 2; ++c) {
            const short8 pa = *reinterpret_cast<const short8*>(
                &Ps[prow * 64 + ((8 * lg + 32 * c) ^ ((prow & 7) << 3))]);
            #pragma unroll
            for (int ef = 0; ef < 4; ++ef) {
                const short8 vb = *reinterpret_cast<const short8*>(
                    &Vt[buf][(16 * ef + lr) * 64 + ((8 * lg + 32 * c) ^ ((lr & 7) << 3))]);
                o[ef] = __builtin_amdgcn_mfma_f32_16x16x32_bf16(pa, vb, o[ef], 0, 0, 0);
            }
            lsumf = __builtin_amdgcn_mfma_f32_16x16x32_bf16(pa, ones8, lsumf, 0, 0, 0);
        }

        // end of iter: staged tile landed, all LDS reads retired
        asm volatile("s_waitcnt vmcnt(0) lgkmcnt(0)" ::: "memory");
        __builtin_amdgcn_sched_barrier(0);
        __builtin_amdgcn_s_barrier();
        __builtin_amdgcn_sched_barrier(0);
        buf ^= 1;
    }

    const int b = bh / H_, h = bh % H_;
    #pragma unroll
    for (int r = 0; r < 4; ++r) {
        const int t = qt * 128 + 16 * w + 4 * lg + r;
        const float inv = 1.0f / lsumf[r];
        #pragma unroll
        for (int ef = 0; ef < 4; ++ef)
            aob[((size_t)t * B_ + b) * D_ + h * HD_ + 16 * ef + lr] =
                f2bf(o[ef][r] * inv);
    }
}

// ---------------------------------------------------------------------------
extern "C" void kernel_launch(void* const* d_in, const int* in_sizes, int n_in,
                              void* d_out, int out_size, void* d_ws, size_t ws_size,
                              hipStream_t stream)
{
    const float* query = (const float*)d_in[0];
    const float* keyi  = (const float*)d_in[1];
    const float* value = (const float*)d_in[2];
    const int*   lsp   = (const int*)  d_in[3];
    const float* Wq  = (const float*)d_in[4],  *bq  = (const float*)d_in[5];
    const float* Wk  = (const float*)d_in[6],  *bk  = (const float*)d_in[7];
    const float* Wv  = (const float*)d_in[8],  *bv  = (const float*)d_in[9];
    const float* Wqm = (const float*)d_in[10], *bqm = (const float*)d_in[11];
    const float* Wkm = (const float*)d_in[12], *bkm = (const float*)d_in[13];
    const float* Wvm = (const float*)d_in[14], *bvm = (const float*)d_in[15];
    const float* Wo  = (const float*)d_in[16], *bo  = (const float*)d_in[17];

    unsigned short* ws = (unsigned short*)d_ws;
    unsigned short* xb  = ws;                       // 3*XSZ
    unsigned short* wb  = xb + 3 * XSZ;             // 7*WSZ
    unsigned short* qh  = wb + 7 * WSZ;             // XSZ
    unsigned short* kh  = qh + XSZ;                 // XSZ
    unsigned short* vt  = kh + XSZ;                 // XSZ
    unsigned short* aob = vt + XSZ;                 // XSZ

    dim3 gc_(512, 10);
    convert_kernel<<<gc_, 256, 0, stream>>>(query, keyi, value,
                                            Wq, Wk, Wv, Wqm, Wkm, Wvm, Wo, xb);

    qkv_gemm<<<1152, 256, 0, stream>>>(xb, wb, lsp, bq, bk, bv, bqm, bkm, bvm,
                                       qh, kh, vt);

    attn_kernel_bf16<<<768, 512, 0, stream>>>(qh, kh, vt, aob);

    out_gemm<<<384, 256, 0, stream>>>(aob, wb + 6 * WSZ, bo, (float*)d_out);
}

// Round 10
// 168.512 us; speedup vs baseline: 1.2313x; 1.1124x over previous
//
#include <hip/hip_runtime.h>

#define T_  1024
#define B_  8
#define D_  768
#define H_  12
#define HD_ 64
#define BH_ 96
#define M_  8192           // T_*B_
#define XSZ 6291456ull     // T_*B_*D_
#define WSZ 589824ull      // D_*D_

typedef __attribute__((ext_vector_type(8))) short short8;
typedef __attribute__((ext_vector_type(4))) float f32x4;

__device__ __forceinline__ unsigned short f2bf(float f) {
    unsigned int u = __float_as_uint(f);
    u += 0x7FFF + ((u >> 16) & 1);          // round-to-nearest-even
    return (unsigned short)(u >> 16);
}

__device__ __forceinline__ void g2lds16(const unsigned short* g, unsigned short* l) {
    __builtin_amdgcn_global_load_lds(
        (const __attribute__((address_space(1))) unsigned int*)(g),
        (__attribute__((address_space(3))) unsigned int*)(l),
        16, 0, 0);
}

// ---------------------------------------------------------------------------
// Kernel 0: fp32 -> bf16 conversion of X (q,k,v) and the 7 weight matrices.
// ---------------------------------------------------------------------------
__global__ __launch_bounds__(256)
void convert_kernel(const float* __restrict__ q, const float* __restrict__ k,
                    const float* __restrict__ v,
                    const float* __restrict__ wq, const float* __restrict__ wk,
                    const float* __restrict__ wv, const float* __restrict__ wqm,
                    const float* __restrict__ wkm, const float* __restrict__ wvm,
                    const float* __restrict__ wo,
                    unsigned short* __restrict__ dst)
{
    const int seg = blockIdx.y;
    const float* s; size_t off, n;
    switch (seg) {
        case 0: s = q;   off = 0;               n = XSZ; break;
        case 1: s = k;   off = XSZ;             n = XSZ; break;
        case 2: s = v;   off = 2*XSZ;           n = XSZ; break;
        case 3: s = wq;  off = 3*XSZ;           n = WSZ; break;
        case 4: s = wk;  off = 3*XSZ +   WSZ;   n = WSZ; break;
        case 5: s = wv;  off = 3*XSZ + 2*WSZ;   n = WSZ; break;
        case 6: s = wqm; off = 3*XSZ + 3*WSZ;   n = WSZ; break;
        case 7: s = wkm; off = 3*XSZ + 4*WSZ;   n = WSZ; break;
        case 8: s = wvm; off = 3*XSZ + 5*WSZ;   n = WSZ; break;
        default:s = wo;  off = 3*XSZ + 6*WSZ;   n = WSZ; break;
    }
    unsigned short* d = dst + off;
    const size_t stride = (size_t)gridDim.x * blockDim.x;
    for (size_t i = (size_t)blockIdx.x * blockDim.x + threadIdx.x; i < n / 4; i += stride) {
        const float4 f = reinterpret_cast<const float4*>(s)[i];
        ushort4 o;
        o.x = f2bf(f.x); o.y = f2bf(f.y); o.z = f2bf(f.z); o.w = f2bf(f.w);
        reinterpret_cast<ushort4*>(d)[i] = o;
    }
}

// ---------------------------------------------------------------------------
// Shared GEMM core: C(128x128) = A(128xK) @ B(128xK)^T, bf16 MFMA 16x16x32,
// K=768, BK=32, 4 waves (2x2 quadrants).
// 3 LDS buffers (48 KB -> 3 blocks/CU), DEPTH-2 prefetch with COUNTED vmcnt:
// steady state waits vmcnt(8) (stages ks+1,ks+2 = 4 insts each in flight);
// stage flight = 2 full K-steps (~800 cy >= HBM latency) AND 12 waves/CU TLP.
// Coalesced staging (16 rows x 64B per wave-inst = 16 lines, optimal);
// 2-bit chunk XOR c ^= (row>>1)&3 applied as pre-swizzled GLOBAL source +
// swizzled ds_read (rule 21) -> conflict-free-floor fragment reads.
// ---------------------------------------------------------------------------
__device__ __forceinline__ void stage_tile32(const unsigned short* __restrict__ A,
                                             const unsigned short* __restrict__ B,
                                             int m0, int n0, int ks,
                                             unsigned short* lds, int buf, int tid)
{
    const int w = tid >> 6, l = tid & 63;
    const int rsub = l >> 2;                        // row within 16-row group
    const int cg   = (l & 3) ^ ((l >> 3) & 3);      // pre-swizzled global chunk
    const int koff = ks * 32 + cg * 8;
    #pragma unroll
    for (int p = 0; p < 2; ++p) {
        const int rbase = p * 64 + w * 16;          // wave-uniform
        const int row   = rbase + rsub;
        g2lds16(&A[(size_t)(m0 + row) * D_ + koff],
                &lds[buf * 8192 + rbase * 32]);
        g2lds16(&B[(size_t)(n0 + row) * D_ + koff],
                &lds[buf * 8192 + 4096 + rbase * 32]);
    }
}

__device__ __forceinline__ void mfma_step32(const unsigned short* lds, int buf,
                                            int wr, int wc, int lr, int lg,
                                            f32x4 acc[4][4])
{
    const int slot = (lg ^ ((lr >> 1) & 3)) * 8;    // (row>>1)&3 == (lr>>1)&3
    short8 a[4], b[4];
    #pragma unroll
    for (int m = 0; m < 4; ++m)
        a[m] = *reinterpret_cast<const short8*>(
            &lds[buf * 8192 + (wr * 64 + 16 * m + lr) * 32 + slot]);
    #pragma unroll
    for (int n = 0; n < 4; ++n)
        b[n] = *reinterpret_cast<const short8*>(
            &lds[buf * 8192 + 4096 + (wc * 64 + 16 * n + lr) * 32 + slot]);
    #pragma unroll
    for (int m = 0; m < 4; ++m)
        #pragma unroll
        for (int n = 0; n < 4; ++n)
            acc[m][n] = __builtin_amdgcn_mfma_f32_16x16x32_bf16(a[m], b[n], acc[m][n], 0, 0, 0);
}

// 24 K-steps, buffers ks%3, depth-2 counted vmcnt.
// Top wait: vmcnt(8) -> stage(ks) landed, ks+1,ks+2 stay in flight; tail
// ks=22/23 -> vmcnt(4)/(0).  After compute: lgkmcnt(0)+barrier retires all
// waves' ds_reads of buf ks%3, then stage(ks+3) safely overwrites it.
#define GEMM_CORE(Aptr, Bptr)                                                  \
    f32x4 acc[4][4];                                                           \
    _Pragma("unroll") for (int m = 0; m < 4; ++m)                              \
        _Pragma("unroll") for (int n = 0; n < 4; ++n)                          \
            acc[m][n] = (f32x4){0.f, 0.f, 0.f, 0.f};                           \
    stage_tile32(Aptr, Bptr, m0, n0, 0, lds, 0, tid);                          \
    stage_tile32(Aptr, Bptr, m0, n0, 1, lds, 1, tid);                          \
    stage_tile32(Aptr, Bptr, m0, n0, 2, lds, 2, tid);                          \
    for (int ks = 0; ks < 24; ++ks) {                                          \
        if (ks < 22)       { asm volatile("s_waitcnt vmcnt(8) lgkmcnt(0)" ::: "memory"); } \
        else if (ks == 22) { asm volatile("s_waitcnt vmcnt(4) lgkmcnt(0)" ::: "memory"); } \
        else               { asm volatile("s_waitcnt vmcnt(0) lgkmcnt(0)" ::: "memory"); } \
        __builtin_amdgcn_sched_barrier(0);                                     \
        __builtin_amdgcn_s_barrier();                                          \
        __builtin_amdgcn_sched_barrier(0);                                     \
        mfma_step32(lds, ks % 3, wr, wc, lr, lg, acc);                         \
        asm volatile("s_waitcnt lgkmcnt(0)" ::: "memory");                     \
        __builtin_amdgcn_sched_barrier(0);                                     \
        __builtin_amdgcn_s_barrier();                                          \
        __builtin_amdgcn_sched_barrier(0);                                     \
        if (ks < 21) stage_tile32(Aptr, Bptr, m0, n0, ks + 3, lds, ks % 3, tid); \
    }

// ---------------------------------------------------------------------------
// Kernel 1: QKV projection GEMM (bf16 MFMA).  1-D grid, XCD-swizzled.
// q,k -> head layout [bh][t][64]; v -> transposed [bh][64][t].
// q scale folds hd^-0.5 AND log2(e): softmax runs in exp2 domain.
// ---------------------------------------------------------------------------
__global__ __launch_bounds__(256)
void qkv_gemm(const unsigned short* __restrict__ xb,
              const unsigned short* __restrict__ wb,
              const int* __restrict__ ls_ptr,
              const float* __restrict__ bq,  const float* __restrict__ bk,
              const float* __restrict__ bv,  const float* __restrict__ bqm,
              const float* __restrict__ bkm, const float* __restrict__ bvm,
              unsigned short* __restrict__ qh, unsigned short* __restrict__ kh,
              unsigned short* __restrict__ vt)
{
    __shared__ unsigned short lds[24576];   // 3 x 16 KB buffers (A+B)
    const int bid = blockIdx.x;                       // 1152 blocks
    const int L   = (bid & 7) * 144 + (bid >> 3);     // bijective XCD swizzle
    const int z   = L / 384;
    const int rem = L - z * 384;
    const int mi  = rem / 6;
    const int ni  = rem - mi * 6;
    const int m0 = mi * 128, n0 = ni * 128;

    const int tid = threadIdx.x;
    const int w = tid >> 6, l = tid & 63, lr = l & 15, lg = l >> 4;
    const int wr = w >> 1, wc = w & 1;

    const bool modal = (m0 >= ls_ptr[0] * B_);
    const unsigned short* A = xb + (size_t)z * XSZ;
    const unsigned short* W = wb + (size_t)(z + (modal ? 3 : 0)) * WSZ;
    const float* bias = modal ? (z == 0 ? bqm : z == 1 ? bkm : bvm)
                              : (z == 0 ? bq  : z == 1 ? bk  : bv);

    GEMM_CORE(A, W)

    float bn[4];
    #pragma unroll
    for (int n = 0; n < 4; ++n) bn[n] = bias[n0 + wc * 64 + 16 * n + lr];

    if (z < 2) {
        unsigned short* dst = (z == 0) ? qh : kh;
        // 0.125 * log2(e): scores emerge in log2 domain for flat softmax
        const float scale = (z == 0) ? 0.18033688011112042f : 1.0f;
        #pragma unroll
        for (int m = 0; m < 4; ++m) {
            const int grb = m0 + wr * 64 + 16 * m + 4 * lg;
            #pragma unroll
            for (int n = 0; n < 4; ++n) {
                const int gc = n0 + wc * 64 + 16 * n + lr;
                const int h = gc >> 6, e = gc & 63;
                #pragma unroll
                for (int j = 0; j < 4; ++j) {
                    const int gr = grb + j, t = gr >> 3, b = gr & 7;
                    dst[((size_t)(b * H_ + h) * T_ + t) * HD_ + e] =
                        f2bf((acc[m][n][j] + bn[n]) * scale);
                }
            }
        }
    } else {
        #pragma unroll
        for (int m = 0; m < 4; ++m) {
            const int grb = m0 + wr * 64 + 16 * m + 4 * lg;
            #pragma unroll
            for (int n = 0; n < 4; ++n) {
                const int gc = n0 + wc * 64 + 16 * n + lr;
                const int h = gc >> 6, e = gc & 63;
                #pragma unroll
                for (int j = 0; j < 4; ++j) {
                    const int gr = grb + j, t = gr >> 3, b = gr & 7;
                    vt[((size_t)(b * H_ + h) * HD_ + e) * T_ + t] =
                        f2bf(acc[m][n][j] + bn[n]);
                }
            }
        }
    }
}

// ---------------------------------------------------------------------------
// Kernel 3: output projection GEMM (bf16 MFMA), fp32 output + bias.
// ---------------------------------------------------------------------------
__global__ __launch_bounds__(256)
void out_gemm(const unsigned short* __restrict__ aob,
              const unsigned short* __restrict__ wo,
              const float* __restrict__ bo, float* __restrict__ out)
{
    __shared__ unsigned short lds[24576];
    const int bid = blockIdx.x;                      // 384 blocks
    const int L   = (bid & 7) * 48 + (bid >> 3);
    const int mi  = L / 6, ni = L - mi * 6;
    const int m0 = mi * 128, n0 = ni * 128;

    const int tid = threadIdx.x;
    const int w = tid >> 6, l = tid & 63, lr = l & 15, lg = l >> 4;
    const int wr = w >> 1, wc = w & 1;

    GEMM_CORE(aob, wo)

    float bn[4];
    #pragma unroll
    for (int n = 0; n < 4; ++n) bn[n] = bo[n0 + wc * 64 + 16 * n + lr];

    #pragma unroll
    for (int m = 0; m < 4; ++m) {
        const int grb = m0 + wr * 64 + 16 * m + 4 * lg;
        #pragma unroll
        for (int n = 0; n < 4; ++n) {
            const int gc = n0 + wc * 64 + 16 * n + lr;
            #pragma unroll
            for (int j = 0; j < 4; ++j) {
                const int gr = grb + j;
                out[(size_t)gr * D_ + gc] = acc[m][n][j] + bn[n];
            }
        }
    }
}

// ---------------------------------------------------------------------------
// Kernel 2: flash attention, bf16 MFMA, flat softmax (exp2 domain).
// 128 q-rows/block, 512 threads (8 waves x 16 rows).  K/V double-buffered
// via global_load_lds; stage(kt+1) issued at top of iter, waited at the end.
// Unchanged from R8.
// ---------------------------------------------------------------------------
__device__ __forceinline__ void stage_kv(const unsigned short* __restrict__ khh,
                                         const unsigned short* __restrict__ vth,
                                         int kt, unsigned short* KsB,
                                         unsigned short* VtB, int w, int l)
{
    const int rbase = w * 8;                    // wave-uniform (8 waves x 8 rows)
    const int row   = rbase + (l >> 3);
    const int cg    = (l & 7) ^ ((l >> 3) & 7); // pre-swizzled global chunk
    g2lds16(&khh[(size_t)(kt * 64 + row) * HD_ + cg * 8], &KsB[rbase * 64]);
    g2lds16(&vth[(size_t)row * T_ + kt * 64 + cg * 8],    &VtB[rbase * 64]);
}

__global__ __launch_bounds__(512)
void attn_kernel_bf16(const unsigned short* __restrict__ qh,
                      const unsigned short* __restrict__ kh,
                      const unsigned short* __restrict__ vt,
                      unsigned short* __restrict__ aob)
{
    const int bid = blockIdx.x;                      // 768 blocks
    const int L   = (bid & 7) * 96 + (bid >> 3);     // 12 heads per XCD
    const int bh  = L >> 3;
    const int qt  = L & 7;                           // 8 q-tiles of 128 rows

    const int tid = threadIdx.x;
    const int w   = tid >> 6;                        // 0..7
    const int l   = tid & 63;
    const int lr  = l & 15;
    const int lg  = l >> 4;

    __shared__ unsigned short Ks[2][4096];   // [buf][64 rows][64] swizzled
    __shared__ unsigned short Vt[2][4096];
    __shared__ unsigned short Ps[8192];      // [128 q][64 s]   swizzled

    const unsigned short* khh = kh + (size_t)bh * T_ * HD_;
    const unsigned short* vth = vt + (size_t)bh * HD_ * T_;
    const size_t qk_head = (size_t)bh * T_ * HD_;

    short8 qf[2];
    #pragma unroll
    for (int c = 0; c < 2; ++c)
        qf[c] = *reinterpret_cast<const short8*>(
            &qh[qk_head + (size_t)(qt * 128 + 16 * w + lr) * HD_ + 8 * lg + 32 * c]);

    const short one_bf = (short)0x3F80;   // bf16 1.0
    const short8 ones8 = {one_bf, one_bf, one_bf, one_bf,
                          one_bf, one_bf, one_bf, one_bf};

    f32x4 o[4];
    #pragma unroll
    for (int ef = 0; ef < 4; ++ef) o[ef] = (f32x4){0.f, 0.f, 0.f, 0.f};
    f32x4 lsumf = (f32x4){0.f, 0.f, 0.f, 0.f};

    stage_kv(khh, vth, 0, Ks[0], Vt[0], w, l);
    asm volatile("s_waitcnt vmcnt(0)" ::: "memory");
    __builtin_amdgcn_s_barrier();

    int buf = 0;
    for (int kt = 0; kt < 16; ++kt) {
        __builtin_amdgcn_sched_barrier(0);
        if (kt < 15)
            stage_kv(khh, vth, kt + 1, Ks[buf ^ 1], Vt[buf ^ 1], w, l);

        // ---- S = Q K^T (log2 domain): 8 MFMA ----
        f32x4 s[4];
        #pragma unroll
        for (int nf = 0; nf < 4; ++nf) s[nf] = (f32x4){0.f, 0.f, 0.f, 0.f};
        #pragma unroll
        for (int c = 0; c < 2; ++c) {
            #pragma unroll
            for (int nf = 0; nf < 4; ++nf) {
                const short8 kb = *reinterpret_cast<const short8*>(
                    &Ks[buf][(16 * nf + lr) * 64 + ((8 * lg + 32 * c) ^ ((lr & 7) << 3))]);
                s[nf] = __builtin_amdgcn_mfma_f32_16x16x32_bf16(qf[c], kb, s[nf], 0, 0, 0);
            }
        }

        // ---- flat softmax: P = exp2(s - 16), no reductions ----
        #pragma unroll
        for (int r = 0; r < 4; ++r) {
            const int q  = 16 * w + 4 * lg + r;
            const int qx = ((4 * lg + r) & 7) << 3;
            #pragma unroll
            for (int nf = 0; nf < 4; ++nf)
                Ps[q * 64 + ((16 * nf + lr) ^ qx)] =
                    f2bf(exp2f(s[nf][r] - 16.0f));
        }
        asm volatile("s_waitcnt lgkmcnt(0)" ::: "memory");
        __builtin_amdgcn_sched_barrier(0);
        __builtin_amdgcn_s_barrier();
        __builtin_amdgcn_sched_barrier(0);

        // ---- O += P V ; lsum += P 1 : 10 MFMA ----
        const int prow = 16 * w + lr;
        #pragma unroll
        for (int c = 0; c < 2; ++c) {
            const short8 pa = *reinterpret_cast<const short8*>(
                &Ps[prow * 64 + ((8 * lg + 32 * c) ^ ((prow & 7) << 3))]);
            #pragma unroll
            for (int ef = 0; ef < 4; ++ef) {
                const short8 vb = *reinterpret_cast<const short8*>(
                    &Vt[buf][(16 * ef + lr) * 64 + ((8 * lg + 32 * c) ^ ((lr & 7) << 3))]);
                o[ef] = __builtin_amdgcn_mfma_f32_16x16x32_bf16(pa, vb, o[ef], 0, 0, 0);
            }
            lsumf = __builtin_amdgcn_mfma_f32_16x16x32_bf16(pa, ones8, lsumf, 0, 0, 0);
        }

        // end of iter: staged tile landed, all LDS reads retired
        asm volatile("s_waitcnt vmcnt(0) lgkmcnt(0)" ::: "memory");
        __builtin_amdgcn_sched_barrier(0);
        __builtin_amdgcn_s_barrier();
        __builtin_amdgcn_sched_barrier(0);
        buf ^= 1;
    }

    const int b = bh / H_, h = bh % H_;
    #pragma unroll
    for (int r = 0; r < 4; ++r) {
        const int t = qt * 128 + 16 * w + 4 * lg + r;
        const float inv = 1.0f / lsumf[r];
        #pragma unroll
        for (int ef = 0; ef < 4; ++ef)
            aob[((size_t)t * B_ + b) * D_ + h * HD_ + 16 * ef + lr] =
                f2bf(o[ef][r] * inv);
    }
}

// ---------------------------------------------------------------------------
extern "C" void kernel_launch(void* const* d_in, const int* in_sizes, int n_in,
                              void* d_out, int out_size, void* d_ws, size_t ws_size,
                              hipStream_t stream)
{
    const float* query = (const float*)d_in[0];
    const float* keyi  = (const float*)d_in[1];
    const float* value = (const float*)d_in[2];
    const int*   lsp   = (const int*)  d_in[3];
    const float* Wq  = (const float*)d_in[4],  *bq  = (const float*)d_in[5];
    const float* Wk  = (const float*)d_in[6],  *bk  = (const float*)d_in[7];
    const float* Wv  = (const float*)d_in[8],  *bv  = (const float*)d_in[9];
    const float* Wqm = (const float*)d_in[10], *bqm = (const float*)d_in[11];
    const float* Wkm = (const float*)d_in[12], *bkm = (const float*)d_in[13];
    const float* Wvm = (const float*)d_in[14], *bvm = (const float*)d_in[15];
    const float* Wo  = (const float*)d_in[16], *bo  = (const float*)d_in[17];

    unsigned short* ws = (unsigned short*)d_ws;
    unsigned short* xb  = ws;                       // 3*XSZ
    unsigned short* wb  = xb + 3 * XSZ;             // 7*WSZ
    unsigned short* qh  = wb + 7 * WSZ;             // XSZ
    unsigned short* kh  = qh + XSZ;                 // XSZ
    unsigned short* vt  = kh + XSZ;                 // XSZ
    unsigned short* aob = vt + XSZ;                 // XSZ

    dim3 gc_(512, 10);
    convert_kernel<<<gc_, 256, 0, stream>>>(query, keyi, value,
                                            Wq, Wk, Wv, Wqm, Wkm, Wvm, Wo, xb);

    qkv_gemm<<<1152, 256, 0, stream>>>(xb, wb, lsp, bq, bk, bv, bqm, bkm, bvm,
                                       qh, kh, vt);

    attn_kernel_bf16<<<768, 512, 0, stream>>>(qh, kh, vt, aob);

    out_gemm<<<384, 256, 0, stream>>>(aob, wb + 6 * WSZ, bo, (float*)d_out);
}